// Round 11
// baseline (625.499 us; speedup 1.0000x reference)
//
#include <hip/hip_runtime.h>

#define T_STEPS 512
#define HID 128
#define ROWS 16   // batch rows per wave-block -> 64 blocks of 1 wave

typedef short bf16x8 __attribute__((ext_vector_type(8)));   // MFMA A/B frag
typedef float f32x4  __attribute__((ext_vector_type(4)));   // MFMA C/D frag
typedef unsigned int u32;
typedef u32 u32x4 __attribute__((ext_vector_type(4)));

// ONE WAVE owns all 128 outputs for 16 batch rows. Row-permuted W:
//   j(t,m) = 32*(t>>1) + 8*(m>>2) + 4*(t&1) + (m&3)
// makes step t's C/D fragment exactly step t+1's B fragment in the SAME lane:
//   C/D: lane(q,r) tile t holds rows m=4q+i  -> j = 32(t>>1)+8q+4(t&1)+i
//   B:   lane(q,r) chunk c needs k=32c+8q+e  -> e=0..3 from tile 2c (i=e),
//                                               e=4..7 from tile 2c+1 (i=e-4)
// so the recurrence runs entirely in registers: NO LDS, NO barriers.

__device__ __forceinline__ u32 cvt_pk_bf16(float s0, float s1) {
    u32 d;  // d.lo = bf16(s0), d.hi = bf16(s1)
    asm("v_cvt_pk_bf16_f32 %0, %1, %2" : "=v"(d) : "v"(s0), "v"(s1));
    return d;
}
__device__ __forceinline__ bf16x8 frag_from(u32 a, u32 b, u32 c, u32 d) {
    u32x4 t = {a, b, c, d};
    return __builtin_bit_cast(bf16x8, t);
}
// tanh(a) = 1 - 2/(exp2(a*2*log2e)+1); saturates correctly at +-inf
__device__ __forceinline__ float tanh_fast(float a) {
    const float e = __builtin_amdgcn_exp2f(a * 2.885390081777926816f);
    const float rc = __builtin_amdgcn_rcpf(e + 1.0f);
    return fmaf(-2.0f, rc, 1.0f);
}

// split 8 f32 into hi/lo bf16 frags (W ~= WH + WL to ~2^-18 rel)
#define SPLIT8(HI, LO, fa, fb) do {                                           \
    u32 h0_ = cvt_pk_bf16(fa.x,fa.y), h1_ = cvt_pk_bf16(fa.z,fa.w);           \
    u32 h2_ = cvt_pk_bf16(fb.x,fb.y), h3_ = cvt_pk_bf16(fb.z,fb.w);           \
    float l0_ = fa.x - __uint_as_float(h0_ << 16);                            \
    float l1_ = fa.y - __uint_as_float(h0_ & 0xffff0000u);                    \
    float l2_ = fa.z - __uint_as_float(h1_ << 16);                            \
    float l3_ = fa.w - __uint_as_float(h1_ & 0xffff0000u);                    \
    float l4_ = fb.x - __uint_as_float(h2_ << 16);                            \
    float l5_ = fb.y - __uint_as_float(h2_ & 0xffff0000u);                    \
    float l6_ = fb.z - __uint_as_float(h3_ << 16);                            \
    float l7_ = fb.w - __uint_as_float(h3_ & 0xffff0000u);                    \
    u32 g0_ = cvt_pk_bf16(l0_,l1_), g1_ = cvt_pk_bf16(l2_,l3_);               \
    u32 g2_ = cvt_pk_bf16(l4_,l5_), g3_ = cvt_pk_bf16(l6_,l7_);               \
    HI = frag_from(h0_,h1_,h2_,h3_); LO = frag_from(g0_,g1_,g2_,g3_);         \
} while (0)

#define MFMA(ACC, A, B) \
    ACC = __builtin_amdgcn_mfma_f32_16x16x32_bf16(A, B, ACC, 0, 0, 0);

// ---- per-tile state (all named scalars/vectors: no runtime-indexed arrays)
#define DT(T)                                                                 \
    bf16x8 WH0_##T, WH1_##T, WH2_##T, WH3_##T;                                \
    bf16x8 WL0_##T, WL1_##T, WL2_##T, WL3_##T;                                \
    u32 PK0_##T = 0, PK1_##T = 0;                                             \
    f32x4 ACC_##T;                                                            \
    float4 WIH_##T, BIA_##T;

#define LT(T) do {                                                            \
    const int row_ = 32*((T)>>1) + 8*(r>>2) + 4*((T)&1) + (r&3);              \
    const float* p_ = W_hh + (size_t)row_ * HID + q * 8;                      \
    float4 fa_, fb_;                                                          \
    fa_ = *(const float4*)(p_ +  0); fb_ = *(const float4*)(p_ +  4);         \
    SPLIT8(WH0_##T, WL0_##T, fa_, fb_);                                       \
    fa_ = *(const float4*)(p_ + 32); fb_ = *(const float4*)(p_ + 36);         \
    SPLIT8(WH1_##T, WL1_##T, fa_, fb_);                                       \
    fa_ = *(const float4*)(p_ + 64); fb_ = *(const float4*)(p_ + 68);         \
    SPLIT8(WH2_##T, WL2_##T, fa_, fb_);                                       \
    fa_ = *(const float4*)(p_ + 96); fb_ = *(const float4*)(p_ + 100);        \
    SPLIT8(WH3_##T, WL3_##T, fa_, fb_);                                       \
    const int jb_ = 32*((T)>>1) + 8*q + 4*((T)&1);                            \
    WIH_##T = *(const float4*)(W_ih + jb_);                                   \
    const float4 bi_ = *(const float4*)(b_ih + jb_);                          \
    const float4 bh_ = *(const float4*)(b_hh + jb_);                          \
    BIA_##T.x = bi_.x + bh_.x; BIA_##T.y = bi_.y + bh_.y;                     \
    BIA_##T.z = bi_.z + bh_.z; BIA_##T.w = bi_.w + bh_.w;                     \
} while (0)

#define INIT(T)                                                               \
    ACC_##T[0] = fmaf(xt, WIH_##T.x, BIA_##T.x);                              \
    ACC_##T[1] = fmaf(xt, WIH_##T.y, BIA_##T.y);                              \
    ACC_##T[2] = fmaf(xt, WIH_##T.z, BIA_##T.z);                              \
    ACC_##T[3] = fmaf(xt, WIH_##T.w, BIA_##T.w);

#define FIN(T) do {                                                           \
    const float h0_ = tanh_fast(ACC_##T[0]);                                  \
    const float h1_ = tanh_fast(ACC_##T[1]);                                  \
    const float h2_ = tanh_fast(ACC_##T[2]);                                  \
    const float h3_ = tanh_fast(ACC_##T[3]);                                  \
    PK0_##T = cvt_pk_bf16(h0_, h1_); PK1_##T = cvt_pk_bf16(h2_, h3_);         \
} while (0)

__global__ __launch_bounds__(64, 1)
__attribute__((amdgpu_waves_per_eu(1, 1)))
void rnn_wave_kernel(const float* __restrict__ x,
                     const float* __restrict__ W_ih,
                     const float* __restrict__ W_hh,
                     const float* __restrict__ b_ih,
                     const float* __restrict__ b_hh,
                     const float* __restrict__ W_out,
                     const float* __restrict__ b_out,
                     float* __restrict__ y)
{
    const int l  = threadIdx.x;     // 0..63
    const int q  = l >> 4;          // lane quarter
    const int r  = l & 15;          // batch row (C col / B col / A row)
    const int b0 = blockIdx.x * ROWS;

    DT(0) DT(1) DT(2) DT(3) DT(4) DT(5) DT(6) DT(7)
    LT(0); LT(1); LT(2); LT(3); LT(4); LT(5); LT(6); LT(7);

    const float* __restrict__ xrow = x + (size_t)(b0 + r) * T_STEPS;
    float xt = xrow[0];

    for (int t = 0; t < T_STEPS; ++t) {
        // B-frags straight from previous step's packed registers
        const bf16x8 B0 = frag_from(PK0_0, PK1_0, PK0_1, PK1_1);
        const bf16x8 B1 = frag_from(PK0_2, PK1_2, PK0_3, PK1_3);
        const bf16x8 B2 = frag_from(PK0_4, PK1_4, PK0_5, PK1_5);
        const bf16x8 B3 = frag_from(PK0_6, PK1_6, PK0_7, PK1_7);

        const float xn = xrow[(t < T_STEPS - 1) ? t + 1 : T_STEPS - 1];

        INIT(0) INIT(1) INIT(2) INIT(3) INIT(4) INIT(5) INIT(6) INIT(7)

        // 64 MFMAs; each ACC touched every 8 issues (dep spacing > latency)
        MFMA(ACC_0, WH0_0, B0) MFMA(ACC_1, WH0_1, B0)
        MFMA(ACC_2, WH0_2, B0) MFMA(ACC_3, WH0_3, B0)
        MFMA(ACC_4, WH0_4, B0) MFMA(ACC_5, WH0_5, B0)
        MFMA(ACC_6, WH0_6, B0) MFMA(ACC_7, WH0_7, B0)

        MFMA(ACC_0, WH1_0, B1) MFMA(ACC_1, WH1_1, B1)
        MFMA(ACC_2, WH1_2, B1) MFMA(ACC_3, WH1_3, B1)
        MFMA(ACC_4, WH1_4, B1) MFMA(ACC_5, WH1_5, B1)
        MFMA(ACC_6, WH1_6, B1) MFMA(ACC_7, WH1_7, B1)

        MFMA(ACC_0, WH2_0, B2) MFMA(ACC_1, WH2_1, B2)
        MFMA(ACC_2, WH2_2, B2) MFMA(ACC_3, WH2_3, B2)
        MFMA(ACC_4, WH2_4, B2) MFMA(ACC_5, WH2_5, B2)
        MFMA(ACC_6, WH2_6, B2) MFMA(ACC_7, WH2_7, B2)

        MFMA(ACC_0, WH3_0, B3) MFMA(ACC_1, WH3_1, B3)
        MFMA(ACC_2, WH3_2, B3) MFMA(ACC_3, WH3_3, B3)
        MFMA(ACC_4, WH3_4, B3) MFMA(ACC_5, WH3_5, B3)
        MFMA(ACC_6, WH3_6, B3) MFMA(ACC_7, WH3_7, B3)

        MFMA(ACC_0, WL0_0, B0) MFMA(ACC_1, WL0_1, B0)
        MFMA(ACC_2, WL0_2, B0) MFMA(ACC_3, WL0_3, B0)
        MFMA(ACC_4, WL0_4, B0) MFMA(ACC_5, WL0_5, B0)
        MFMA(ACC_6, WL0_6, B0) MFMA(ACC_7, WL0_7, B0)

        MFMA(ACC_0, WL1_0, B1) MFMA(ACC_1, WL1_1, B1)
        MFMA(ACC_2, WL1_2, B1) MFMA(ACC_3, WL1_3, B1)
        MFMA(ACC_4, WL1_4, B1) MFMA(ACC_5, WL1_5, B1)
        MFMA(ACC_6, WL1_6, B1) MFMA(ACC_7, WL1_7, B1)

        MFMA(ACC_0, WL2_0, B2) MFMA(ACC_1, WL2_1, B2)
        MFMA(ACC_2, WL2_2, B2) MFMA(ACC_3, WL2_3, B2)
        MFMA(ACC_4, WL2_4, B2) MFMA(ACC_5, WL2_5, B2)
        MFMA(ACC_6, WL2_6, B2) MFMA(ACC_7, WL2_7, B2)

        MFMA(ACC_0, WL3_0, B3) MFMA(ACC_1, WL3_1, B3)
        MFMA(ACC_2, WL3_2, B3) MFMA(ACC_3, WL3_3, B3)
        MFMA(ACC_4, WL3_4, B3) MFMA(ACC_5, WL3_5, B3)
        MFMA(ACC_6, WL3_6, B3) MFMA(ACC_7, WL3_7, B3)

        FIN(0); FIN(1); FIN(2); FIN(3); FIN(4); FIN(5); FIN(6); FIN(7);

        xt = xn;
    }

    // ---- y[b0+r] = sum_j W_out[j] * h_last[j] + b_out
    float v = 0.0f;
#define EPI(T) do {                                                           \
    const int jb_ = 32*((T)>>1) + 8*q + 4*((T)&1);                            \
    const float4 wo_ = *(const float4*)(W_out + jb_);                         \
    v = fmaf(wo_.x, __uint_as_float(PK0_##T << 16),          v);              \
    v = fmaf(wo_.y, __uint_as_float(PK0_##T & 0xffff0000u),  v);              \
    v = fmaf(wo_.z, __uint_as_float(PK1_##T << 16),          v);              \
    v = fmaf(wo_.w, __uint_as_float(PK1_##T & 0xffff0000u),  v);              \
} while (0)
    EPI(0); EPI(1); EPI(2); EPI(3); EPI(4); EPI(5); EPI(6); EPI(7);

    v += __shfl_xor(v, 16, 64);
    v += __shfl_xor(v, 32, 64);
    if (l < 16) y[b0 + r] = v + b_out[0];
}

extern "C" void kernel_launch(void* const* d_in, const int* in_sizes, int n_in,
                              void* d_out, int out_size, void* d_ws, size_t ws_size,
                              hipStream_t stream)
{
    const float* x     = (const float*)d_in[0];
    const float* W_ih  = (const float*)d_in[1];
    const float* W_hh  = (const float*)d_in[2];
    const float* b_ih  = (const float*)d_in[3];
    const float* b_hh  = (const float*)d_in[4];
    const float* W_out = (const float*)d_in[5];
    const float* b_out = (const float*)d_in[6];
    float* y = (float*)d_out;

    const int B = in_sizes[0] / T_STEPS;   // 1024
    rnn_wave_kernel<<<B / ROWS, 64, 0, stream>>>(x, W_ih, W_hh, b_ih, b_hh,
                                                 W_out, b_out, y);
}

// Round 13
// 199.307 us; speedup vs baseline: 3.1384x; 3.1384x over previous
//
#include <hip/hip_runtime.h>

#define T_STEPS 512
#define HID 128
#define ROWS 16   // batch rows per block -> 64 blocks

typedef short bf16x8 __attribute__((ext_vector_type(8)));   // MFMA A/B frag
typedef float f32x4  __attribute__((ext_vector_type(4)));   // MFMA C/D frag
typedef unsigned int u32;
typedef u32 u32x4 __attribute__((ext_vector_type(4)));

// 512 threads = 8 waves = 2 waves/SIMD. Wave w owns j-tile [16w, 16w+16):
// 8 MFMA + 4 ds_read_b128 + 1 ds_write per step. R8-R11 established per-wave
// cost ~ MFMA_count*34cyc (latency not hidden within a wave); two waves per
// SIMD hide each other's MFMA/LDS latency, and 8 MFMA/wave is the minimum
// for full k with the 2-term split.

__device__ __forceinline__ u32 cvt_pk_bf16(float s0, float s1) {
    u32 d;  // d.lo = bf16(s0), d.hi = bf16(s1)
    asm("v_cvt_pk_bf16_f32 %0, %1, %2" : "=v"(d) : "v"(s0), "v"(s1));
    return d;
}
__device__ __forceinline__ bf16x8 frag_from(u32 a, u32 b, u32 c, u32 d) {
    u32x4 t = {a, b, c, d};
    return __builtin_bit_cast(bf16x8, t);
}
// tanh(a) = 1 - 2/(exp2(2a*log2e)+1); saturates correctly at +-inf
__device__ __forceinline__ float tanh_fast(float a) {
    const float e  = __builtin_amdgcn_exp2f(a * 2.885390081777926816f);
    const float rc = __builtin_amdgcn_rcpf(e + 1.0f);
    return fmaf(-2.0f, rc, 1.0f);
}

// split 8 f32 into hi/lo bf16 frags (W ~= WH + WL, residual ~2^-18 rel)
#define SPLIT8(HI, LO, fa, fb) do {                                           \
    u32 h0_ = cvt_pk_bf16(fa.x,fa.y), h1_ = cvt_pk_bf16(fa.z,fa.w);           \
    u32 h2_ = cvt_pk_bf16(fb.x,fb.y), h3_ = cvt_pk_bf16(fb.z,fb.w);           \
    float l0_ = fa.x - __uint_as_float(h0_ << 16);                            \
    float l1_ = fa.y - __uint_as_float(h0_ & 0xffff0000u);                    \
    float l2_ = fa.z - __uint_as_float(h1_ << 16);                            \
    float l3_ = fa.w - __uint_as_float(h1_ & 0xffff0000u);                    \
    float l4_ = fb.x - __uint_as_float(h2_ << 16);                            \
    float l5_ = fb.y - __uint_as_float(h2_ & 0xffff0000u);                    \
    float l6_ = fb.z - __uint_as_float(h3_ << 16);                            \
    float l7_ = fb.w - __uint_as_float(h3_ & 0xffff0000u);                    \
    u32 g0_ = cvt_pk_bf16(l0_,l1_), g1_ = cvt_pk_bf16(l2_,l3_);               \
    u32 g2_ = cvt_pk_bf16(l4_,l5_), g3_ = cvt_pk_bf16(l6_,l7_);               \
    HI = frag_from(h0_,h1_,h2_,h3_); LO = frag_from(g0_,g1_,g2_,g3_);         \
} while (0)

#define MFMA(ACC, A, B) \
    ACC = __builtin_amdgcn_mfma_f32_16x16x32_bf16(A, B, ACC, 0, 0, 0);

// LDS: h buf0 @0, h buf1 @4096 ([16 r][128 j] bf16, byte ^= (r&7)<<4);
//      red @8192 ([8 w][16 r] f32)
#define LDS_BYTES (8192 + 512)

__global__ __launch_bounds__(512, 1)
__attribute__((amdgpu_waves_per_eu(2, 2)))
void rnn_mfma8_kernel(const float* __restrict__ x,
                      const float* __restrict__ W_ih,
                      const float* __restrict__ W_hh,
                      const float* __restrict__ b_ih,
                      const float* __restrict__ b_hh,
                      const float* __restrict__ W_out,
                      const float* __restrict__ b_out,
                      float* __restrict__ y)
{
    __shared__ __align__(16) char lds[LDS_BYTES];

    const int tid = threadIdx.x;
    const int w   = tid >> 6;        // wave 0..7: j-tile [16w, 16w+16)
    const int l   = tid & 63;
    const int q   = l >> 4;          // lane quarter (k-group / C row group)
    const int r   = l & 15;          // batch row (A row m / B col n / C col n)
    const int b0  = blockIdx.x * ROWS;

    // ---- zero h buf0 (4 KB, 512 threads x 8 B)
    *(uint2*)&lds[tid * 8] = make_uint2(0u, 0u);

    // ---- W_hh A-frags for tile w: lane(q,r) holds A[m=r][k=32c+8q+e]
    bf16x8 WH0, WH1, WH2, WH3, WL0, WL1, WL2, WL3;
    {
        const float* p = W_hh + (size_t)(16 * w + r) * HID + 8 * q;
        float4 fa, fb;
        fa = *(const float4*)(p +  0); fb = *(const float4*)(p +   4); SPLIT8(WH0, WL0, fa, fb);
        fa = *(const float4*)(p + 32); fb = *(const float4*)(p +  36); SPLIT8(WH1, WL1, fa, fb);
        fa = *(const float4*)(p + 64); fb = *(const float4*)(p +  68); SPLIT8(WH2, WL2, fa, fb);
        fa = *(const float4*)(p + 96); fb = *(const float4*)(p + 100); SPLIT8(WH3, WL3, fa, fb);
    }

    // ---- per-lane constants for this lane's 4 outputs j0..j0+3
    const int j0 = 16 * w + 4 * q;
    const float4 wih = *(const float4*)(W_ih + j0);
    float4 bias;
    {
        const float4 bi = *(const float4*)(b_ih + j0);
        const float4 bh = *(const float4*)(b_hh + j0);
        bias.x = bi.x + bh.x; bias.y = bi.y + bh.y;
        bias.z = bi.z + bh.z; bias.w = bi.w + bh.w;
    }

    // ---- swizzled LDS offsets
    const int swz   = (r & 7) << 4;
    const int voff0 = (r*256 + q*16      ) ^ swz;   // B chunk 0
    const int voff1 = (r*256 + q*16 +  64) ^ swz;   // B chunk 1
    const int voff2 = (r*256 + q*16 + 128) ^ swz;   // B chunk 2
    const int voff3 = (r*256 + q*16 + 192) ^ swz;   // B chunk 3
    const int woff  = (r*256 + 32*w + 8*q) ^ swz;   // h write (8 B)

    const float* __restrict__ xrow = x + (size_t)(b0 + r) * T_STEPS;
    float xt = xrow[0];
    f32x4 hv;

    __syncthreads();

    u32 rb = 0, wb = 4096;
    for (int t = 0; t < T_STEPS; ++t) {
        const bf16x8 B0 = *(const bf16x8*)&lds[rb + voff0];
        const bf16x8 B1 = *(const bf16x8*)&lds[rb + voff1];
        const bf16x8 B2 = *(const bf16x8*)&lds[rb + voff2];
        const bf16x8 B3 = *(const bf16x8*)&lds[rb + voff3];
        const float xn = xrow[(t < T_STEPS - 1) ? t + 1 : T_STEPS - 1];

        f32x4 a0, a1, a2, a3;
        a0[0] = fmaf(xt, wih.x, bias.x); a0[1] = fmaf(xt, wih.y, bias.y);
        a0[2] = fmaf(xt, wih.z, bias.z); a0[3] = fmaf(xt, wih.w, bias.w);
        a1 = (f32x4)(0.0f); a2 = (f32x4)(0.0f); a3 = (f32x4)(0.0f);

        // 8 MFMAs, 4 independent chains of depth 2
        MFMA(a0, WH0, B0) MFMA(a1, WH1, B1) MFMA(a2, WH2, B2) MFMA(a3, WH3, B3)
        MFMA(a0, WL0, B0) MFMA(a1, WL1, B1) MFMA(a2, WL2, B2) MFMA(a3, WL3, B3)

        const f32x4 s = (a0 + a1) + (a2 + a3);
        hv[0] = tanh_fast(s[0]); hv[1] = tanh_fast(s[1]);
        hv[2] = tanh_fast(s[2]); hv[3] = tanh_fast(s[3]);

        *(uint2*)&lds[wb + woff] =
            make_uint2(cvt_pk_bf16(hv[0], hv[1]), cvt_pk_bf16(hv[2], hv[3]));

        xt = xn;
        rb ^= 4096; wb ^= 4096;
        __syncthreads();
    }

    // ---- y[b0+r] = sum_j W_out[j] * h_last[j] + b_out
    const float4 wo = *(const float4*)(W_out + j0);
    float v = wo.x*hv[0] + wo.y*hv[1] + wo.z*hv[2] + wo.w*hv[3];
    v += __shfl_xor(v, 16, 64);
    v += __shfl_xor(v, 32, 64);          // lane r: sum over this tile's 16 j
    if (l < 16) *(float*)&lds[8192 + (w * 16 + r) * 4] = v;
    __syncthreads();
    if (tid < 16) {
        float s = 0.0f;
        #pragma unroll
        for (int ww = 0; ww < 8; ++ww)
            s += *(const float*)&lds[8192 + (ww * 16 + tid) * 4];
        y[b0 + tid] = s + b_out[0];
    }
}

extern "C" void kernel_launch(void* const* d_in, const int* in_sizes, int n_in,
                              void* d_out, int out_size, void* d_ws, size_t ws_size,
                              hipStream_t stream)
{
    const float* x     = (const float*)d_in[0];
    const float* W_ih  = (const float*)d_in[1];
    const float* W_hh  = (const float*)d_in[2];
    const float* b_ih  = (const float*)d_in[3];
    const float* b_hh  = (const float*)d_in[4];
    const float* W_out = (const float*)d_in[5];
    const float* b_out = (const float*)d_in[6];
    float* y = (float*)d_out;

    const int B = in_sizes[0] / T_STEPS;   // 1024
    rnn_mfma8_kernel<<<B / ROWS, 512, 0, stream>>>(x, W_ih, W_hh, b_ih, b_hh,
                                                   W_out, b_out, y);
}